// Round 1
// baseline (374.629 us; speedup 1.0000x reference)
//
#include <hip/hip_runtime.h>
#include <hip/hip_bf16.h>
#include <stdint.h>

#define M_DIM 8192
#define N_DIM 4096
#define K_DIM 4096

typedef int i32x4 __attribute__((ext_vector_type(4)));

// ---------------- init: zero the two absmax slots ----------------
__global__ void w8a8_init_kernel(unsigned* slots) {
    if (threadIdx.x < 2) slots[threadIdx.x] = 0u;
}

// ---------------- absmax reduction (float4 + wave reduce + atomic) ----------------
__global__ void w8a8_absmax_kernel(const float* __restrict__ p, int n4, unsigned* slot) {
    int idx = blockIdx.x * blockDim.x + threadIdx.x;
    int stride = gridDim.x * blockDim.x;
    float m = 0.f;
    const float4* p4 = (const float4*)p;
    for (int i = idx; i < n4; i += stride) {
        float4 v = p4[i];
        m = fmaxf(m, fmaxf(fmaxf(fabsf(v.x), fabsf(v.y)), fmaxf(fabsf(v.z), fabsf(v.w))));
    }
    #pragma unroll
    for (int o = 32; o > 0; o >>= 1)
        m = fmaxf(m, __shfl_xor(m, o, 64));
    if ((threadIdx.x & 63) == 0)
        atomicMax(slot, __float_as_uint(m));   // all values >= 0: bit order == float order
}

// ---------------- quantize: q = rintf(v / scale), pack 4x int8 ----------------
__global__ void w8a8_quant_kernel(const float* __restrict__ in, unsigned* __restrict__ outq,
                                  int n4, const unsigned* __restrict__ slot) {
    float am = __uint_as_float(*slot);
    float scale = fmaxf(am, 1e-5f) / 127.0f;
    int idx = blockIdx.x * blockDim.x + threadIdx.x;
    int stride = gridDim.x * blockDim.x;
    const float4* in4 = (const float4*)in;
    for (int i = idx; i < n4; i += stride) {
        float4 v = in4[i];
        int q0 = (int)rintf(v.x / scale);
        int q1 = (int)rintf(v.y / scale);
        int q2 = (int)rintf(v.z / scale);
        int q3 = (int)rintf(v.w / scale);
        outq[i] = (unsigned)(q0 & 0xff) | ((unsigned)(q1 & 0xff) << 8) |
                  ((unsigned)(q2 & 0xff) << 16) | ((unsigned)(q3 & 0xff) << 24);
    }
}

// ---------------- i8 MFMA GEMM: out[m][n] = sum_k qa[m][k]*qb[n][k], dequant + bias ----------------
// Tile 128x128, BK=128 i8. 4 waves (2x2), each wave 64x64 via 4x4 frags of 16x16x64.
// LDS linear [row][128B]; XOR chunk swizzle (c ^= row&7) applied on global SOURCE and ds_read
// (both-sides rule) so fragment reads are bank-conflict-free while staging stays coalesced.
#define BM 128
#define BN 128
#define BK 128
#define NTILES_N (N_DIM / BN)   // 32

__global__ __launch_bounds__(256, 2) void w8a8_gemm_kernel(
    const signed char* __restrict__ qa,   // [M, K]
    const signed char* __restrict__ qb,   // [N, K]  (weight rows = output cols)
    const float* __restrict__ bias,       // [N]
    const unsigned* __restrict__ slots,   // absmax bits {x, w}
    float* __restrict__ out)              // [M, N]
{
    __shared__ signed char As[BM * BK];
    __shared__ signed char Bs[BN * BK];

    float ax = __uint_as_float(slots[0]);
    float aw = __uint_as_float(slots[1]);
    float sprod = (fmaxf(ax, 1e-5f) / 127.0f) * (fmaxf(aw, 1e-5f) / 127.0f);

    // XCD-aware swizzle: 2048 blocks % 8 == 0 -> simple bijective remap
    int bid = blockIdx.x;
    int cpx = gridDim.x >> 3;
    int swz = (bid & 7) * cpx + (bid >> 3);
    int tm = swz / NTILES_N;
    int tn = swz % NTILES_N;

    int t = threadIdx.x;
    int lane = t & 63;
    int w = t >> 6;
    int wm = (w >> 1) * 64;
    int wn = (w & 1) * 64;
    int fr = lane & 15;   // row within 16x16 frag (A) / col row for B
    int fg = lane >> 4;   // lane group 0..3 (k-chunk)

    const signed char* a_base = qa + (size_t)tm * BM * K_DIM;
    const signed char* b_base = qb + (size_t)tn * BN * K_DIM;

    i32x4 acc[4][4] = {};

    for (int kt = 0; kt < K_DIM; kt += BK) {
        // ---- stage A,B tiles: 4 iters x 256 threads x 16B each = 16KB per tile ----
        #pragma unroll
        for (int i = 0; i < 4; ++i) {
            int row = i * 32 + (t >> 3);      // slot = i*256 + t; row = slot>>3
            int c = t & 7;                    // 16B chunk within 128B row
            int cs = c ^ (row & 7);           // inverse-swizzled global source
            const signed char* ga = a_base + (size_t)row * K_DIM + kt + cs * 16;
            const signed char* gb = b_base + (size_t)row * K_DIM + kt + cs * 16;
            __builtin_amdgcn_global_load_lds(
                (const __attribute__((address_space(1))) void*)ga,
                (__attribute__((address_space(3))) void*)(As + (i * 256 + t) * 16),
                16, 0, 0);
            __builtin_amdgcn_global_load_lds(
                (const __attribute__((address_space(1))) void*)gb,
                (__attribute__((address_space(3))) void*)(Bs + (i * 256 + t) * 16),
                16, 0, 0);
        }
        __syncthreads();

        // ---- compute: 2 k-sub-steps (K=64 each), 16 MFMA per step per wave ----
        #pragma unroll
        for (int kk = 0; kk < 2; ++kk) {
            i32x4 afrag[4], bfrag[4];
            #pragma unroll
            for (int m = 0; m < 4; ++m) {
                int r = wm + m * 16 + fr;
                int chunk = (kk * 4 + fg) ^ (r & 7);   // swizzled read
                afrag[m] = *(const i32x4*)(As + r * BK + chunk * 16);
            }
            #pragma unroll
            for (int n = 0; n < 4; ++n) {
                int r = wn + n * 16 + fr;
                int chunk = (kk * 4 + fg) ^ (r & 7);
                bfrag[n] = *(const i32x4*)(Bs + r * BK + chunk * 16);
            }
            #pragma unroll
            for (int m = 0; m < 4; ++m)
                #pragma unroll
                for (int n = 0; n < 4; ++n)
                    acc[m][n] = __builtin_amdgcn_mfma_i32_16x16x64_i8(
                        afrag[m], bfrag[n], acc[m][n], 0, 0, 0);
        }
        __syncthreads();
    }

    // ---- epilogue: C/D map col=lane&15, row=(lane>>4)*4+reg; dequant + bias ----
    int orow0 = tm * BM + wm + fg * 4;
    int ocol0 = tn * BN + wn + fr;
    #pragma unroll
    for (int n = 0; n < 4; ++n) {
        int col = ocol0 + n * 16;
        float bv = bias[col];
        #pragma unroll
        for (int m = 0; m < 4; ++m) {
            int row = orow0 + m * 16;
            #pragma unroll
            for (int r = 0; r < 4; ++r) {
                out[(size_t)(row + r) * N_DIM + col] = (float)acc[m][n][r] * sprod + bv;
            }
        }
    }
}

extern "C" void kernel_launch(void* const* d_in, const int* in_sizes, int n_in,
                              void* d_out, int out_size, void* d_ws, size_t ws_size,
                              hipStream_t stream) {
    const float* x    = (const float*)d_in[0];   // [4,2048,4096] = [8192,4096]
    const float* wgt  = (const float*)d_in[1];   // [4096,4096]
    const float* bias = (const float*)d_in[2];   // [4096]
    float* out = (float*)d_out;

    char* ws = (char*)d_ws;
    unsigned* slots = (unsigned*)ws;                         // 2 absmax slots
    signed char* qx = (signed char*)(ws + 256);              // 33.5 MB
    signed char* qw = qx + (size_t)M_DIM * K_DIM;            // 16.8 MB

    const int n4_x = (M_DIM * K_DIM) / 4;   // 8388608
    const int n4_w = (N_DIM * K_DIM) / 4;   // 4194304

    w8a8_init_kernel<<<1, 64, 0, stream>>>(slots);
    w8a8_absmax_kernel<<<2048, 256, 0, stream>>>(x,   n4_x, slots + 0);
    w8a8_absmax_kernel<<<1024, 256, 0, stream>>>(wgt, n4_w, slots + 1);
    w8a8_quant_kernel<<<2048, 256, 0, stream>>>(x,   (unsigned*)qx, n4_x, slots + 0);
    w8a8_quant_kernel<<<1024, 256, 0, stream>>>(wgt, (unsigned*)qw, n4_w, slots + 1);
    w8a8_gemm_kernel<<<(M_DIM / BM) * (N_DIM / BN), 256, 0, stream>>>(qx, qw, bias, slots, out);
}

// Round 2
// 242.360 us; speedup vs baseline: 1.5458x; 1.5458x over previous
//
#include <hip/hip_runtime.h>
#include <hip/hip_bf16.h>
#include <stdint.h>

#define M_DIM 8192
#define N_DIM 4096
#define K_DIM 4096

typedef int i32x4 __attribute__((ext_vector_type(4)));

// ws layout:
//   ws + 0    : float finals[2]  = {scale_x, scale_w}
//   ws + 256  : float partials[3072]  (blocks 0..2047 = x, 2048..3071 = w)
//   ws + 16384: qx [M*K] int8, then qw [N*K] int8
#define NB_X 2048
#define NB_W 1024
#define NB_TOT (NB_X + NB_W)

// ---------------- absmax: per-block partial max, no atomics ----------------
__global__ void w8a8_absmax_kernel(const float* __restrict__ x,
                                   const float* __restrict__ w,
                                   float* __restrict__ partials) {
    int b = blockIdx.x;
    const float4* p;
    int n4, bi, nb;
    if (b < NB_X) { p = (const float4*)x; n4 = (M_DIM * K_DIM) / 4; bi = b;        nb = NB_X; }
    else          { p = (const float4*)w; n4 = (N_DIM * K_DIM) / 4; bi = b - NB_X; nb = NB_W; }

    float m = 0.f;
    int stride = nb * 256;
    for (int i = bi * 256 + threadIdx.x; i < n4; i += stride) {
        float4 v = p[i];
        m = fmaxf(m, fmaxf(fmaxf(fabsf(v.x), fabsf(v.y)), fmaxf(fabsf(v.z), fabsf(v.w))));
    }
    #pragma unroll
    for (int o = 32; o > 0; o >>= 1)
        m = fmaxf(m, __shfl_xor(m, o, 64));

    __shared__ float red[4];
    if ((threadIdx.x & 63) == 0) red[threadIdx.x >> 6] = m;
    __syncthreads();
    if (threadIdx.x == 0)
        partials[b] = fmaxf(fmaxf(red[0], red[1]), fmaxf(red[2], red[3]));
}

// ---------------- finalize: reduce partials -> scale (2 blocks) ----------------
__global__ void w8a8_finalize_kernel(const float* __restrict__ partials,
                                     float* __restrict__ finals) {
    int base = (blockIdx.x == 0) ? 0 : NB_X;
    int n    = (blockIdx.x == 0) ? NB_X : NB_W;
    float m = 0.f;
    for (int i = threadIdx.x; i < n; i += 256)
        m = fmaxf(m, partials[base + i]);
    #pragma unroll
    for (int o = 32; o > 0; o >>= 1)
        m = fmaxf(m, __shfl_xor(m, o, 64));
    __shared__ float red[4];
    if ((threadIdx.x & 63) == 0) red[threadIdx.x >> 6] = m;
    __syncthreads();
    if (threadIdx.x == 0) {
        m = fmaxf(fmaxf(red[0], red[1]), fmaxf(red[2], red[3]));
        finals[blockIdx.x] = fmaxf(m, 1e-5f) / 127.0f;   // scale
    }
}

// ---------------- quantize both tensors: q = rintf(v / scale) (IEEE div, exact) ----------------
__global__ void w8a8_quant_kernel(const float* __restrict__ x,
                                  const float* __restrict__ w,
                                  unsigned* __restrict__ qx,
                                  unsigned* __restrict__ qw,
                                  const float* __restrict__ finals) {
    int b = blockIdx.x;
    const float4* in4;
    unsigned* outq;
    int n4, bi, nb;
    float scale;
    if (b < NB_X) { in4 = (const float4*)x; outq = qx; n4 = (M_DIM * K_DIM) / 4; bi = b;        nb = NB_X; scale = finals[0]; }
    else          { in4 = (const float4*)w; outq = qw; n4 = (N_DIM * K_DIM) / 4; bi = b - NB_X; nb = NB_W; scale = finals[1]; }

    int stride = nb * 256;
    for (int i = bi * 256 + threadIdx.x; i < n4; i += stride) {
        float4 v = in4[i];
        int q0 = (int)rintf(v.x / scale);
        int q1 = (int)rintf(v.y / scale);
        int q2 = (int)rintf(v.z / scale);
        int q3 = (int)rintf(v.w / scale);
        outq[i] = (unsigned)(q0 & 0xff) | ((unsigned)(q1 & 0xff) << 8) |
                  ((unsigned)(q2 & 0xff) << 16) | ((unsigned)(q3 & 0xff) << 24);
    }
}

// ---------------- i8 MFMA GEMM (m97 structure, 128x128, BK=128, both-sides XOR swizzle) ----------------
#define BM 128
#define BN 128
#define BK 128
#define NTILES_N (N_DIM / BN)   // 32

__global__ __launch_bounds__(256, 4) void w8a8_gemm_kernel(
    const signed char* __restrict__ qa,   // [M, K]
    const signed char* __restrict__ qb,   // [N, K]
    const float* __restrict__ bias,       // [N]
    const float* __restrict__ finals,     // {scale_x, scale_w}
    float* __restrict__ out)              // [M, N]
{
    __shared__ signed char As[BM * BK];
    __shared__ signed char Bs[BN * BK];

    float sprod = finals[0] * finals[1];

    int bid = blockIdx.x;
    int cpx = gridDim.x >> 3;
    int swz = (bid & 7) * cpx + (bid >> 3);
    int tm = swz / NTILES_N;
    int tn = swz % NTILES_N;

    int t = threadIdx.x;
    int lane = t & 63;
    int w = t >> 6;
    int wm = (w >> 1) * 64;
    int wn = (w & 1) * 64;
    int fr = lane & 15;
    int fg = lane >> 4;

    const signed char* a_base = qa + (size_t)tm * BM * K_DIM;
    const signed char* b_base = qb + (size_t)tn * BN * K_DIM;

    i32x4 acc[4][4] = {};

    for (int kt = 0; kt < K_DIM; kt += BK) {
        #pragma unroll
        for (int i = 0; i < 4; ++i) {
            int row = i * 32 + (t >> 3);
            int c = t & 7;
            int cs = c ^ (row & 7);          // inverse-swizzled global source
            const signed char* ga = a_base + (size_t)row * K_DIM + kt + cs * 16;
            const signed char* gb = b_base + (size_t)row * K_DIM + kt + cs * 16;
            __builtin_amdgcn_global_load_lds(
                (const __attribute__((address_space(1))) void*)ga,
                (__attribute__((address_space(3))) void*)(As + (i * 256 + t) * 16),
                16, 0, 0);
            __builtin_amdgcn_global_load_lds(
                (const __attribute__((address_space(1))) void*)gb,
                (__attribute__((address_space(3))) void*)(Bs + (i * 256 + t) * 16),
                16, 0, 0);
        }
        __syncthreads();

        #pragma unroll
        for (int kk = 0; kk < 2; ++kk) {
            i32x4 afrag[4], bfrag[4];
            #pragma unroll
            for (int m = 0; m < 4; ++m) {
                int r = wm + m * 16 + fr;
                int chunk = (kk * 4 + fg) ^ (r & 7);
                afrag[m] = *(const i32x4*)(As + r * BK + chunk * 16);
            }
            #pragma unroll
            for (int n = 0; n < 4; ++n) {
                int r = wn + n * 16 + fr;
                int chunk = (kk * 4 + fg) ^ (r & 7);
                bfrag[n] = *(const i32x4*)(Bs + r * BK + chunk * 16);
            }
            #pragma unroll
            for (int m = 0; m < 4; ++m)
                #pragma unroll
                for (int n = 0; n < 4; ++n)
                    acc[m][n] = __builtin_amdgcn_mfma_i32_16x16x64_i8(
                        afrag[m], bfrag[n], acc[m][n], 0, 0, 0);
        }
        __syncthreads();
    }

    int orow0 = tm * BM + wm + fg * 4;
    int ocol0 = tn * BN + wn + fr;
    #pragma unroll
    for (int n = 0; n < 4; ++n) {
        int col = ocol0 + n * 16;
        float bv = bias[col];
        #pragma unroll
        for (int m = 0; m < 4; ++m) {
            int row = orow0 + m * 16;
            #pragma unroll
            for (int r = 0; r < 4; ++r) {
                out[(size_t)(row + r) * N_DIM + col] = (float)acc[m][n][r] * sprod + bv;
            }
        }
    }
}

extern "C" void kernel_launch(void* const* d_in, const int* in_sizes, int n_in,
                              void* d_out, int out_size, void* d_ws, size_t ws_size,
                              hipStream_t stream) {
    const float* x    = (const float*)d_in[0];   // [8192, 4096]
    const float* wgt  = (const float*)d_in[1];   // [4096, 4096]
    const float* bias = (const float*)d_in[2];   // [4096]
    float* out = (float*)d_out;

    char* ws = (char*)d_ws;
    float* finals   = (float*)ws;                       // 2 scales
    float* partials = (float*)(ws + 256);               // 3072 floats
    signed char* qx = (signed char*)(ws + 16384);
    signed char* qw = qx + (size_t)M_DIM * K_DIM;

    w8a8_absmax_kernel<<<NB_TOT, 256, 0, stream>>>(x, wgt, partials);
    w8a8_finalize_kernel<<<2, 256, 0, stream>>>(partials, finals);
    w8a8_quant_kernel<<<NB_TOT, 256, 0, stream>>>(x, wgt, (unsigned*)qx, (unsigned*)qw, finals);
    w8a8_gemm_kernel<<<(M_DIM / BM) * (N_DIM / BN), 256, 0, stream>>>(qx, qw, bias, finals, out);
}

// Round 4
// 226.400 us; speedup vs baseline: 1.6547x; 1.0705x over previous
//
#include <hip/hip_runtime.h>
#include <hip/hip_bf16.h>
#include <stdint.h>

#define M_DIM 8192
#define N_DIM 4096
#define K_DIM 4096

typedef int i32x4 __attribute__((ext_vector_type(4)));

#define NB_X 2048
#define NB_W 1024
#define NB_TOT (NB_X + NB_W)

// ---------------- absmax: per-block partial max, no atomics ----------------
__global__ void w8a8_absmax_kernel(const float* __restrict__ x,
                                   const float* __restrict__ w,
                                   float* __restrict__ partials) {
    int b = blockIdx.x;
    const float4* p;
    int n4, bi, nb;
    if (b < NB_X) { p = (const float4*)x; n4 = (M_DIM * K_DIM) / 4; bi = b;        nb = NB_X; }
    else          { p = (const float4*)w; n4 = (N_DIM * K_DIM) / 4; bi = b - NB_X; nb = NB_W; }

    float m = 0.f;
    int stride = nb * 256;
    for (int i = bi * 256 + threadIdx.x; i < n4; i += stride) {
        float4 v = p[i];
        m = fmaxf(m, fmaxf(fmaxf(fabsf(v.x), fabsf(v.y)), fmaxf(fabsf(v.z), fabsf(v.w))));
    }
    #pragma unroll
    for (int o = 32; o > 0; o >>= 1)
        m = fmaxf(m, __shfl_xor(m, o, 64));

    __shared__ float red[4];
    if ((threadIdx.x & 63) == 0) red[threadIdx.x >> 6] = m;
    __syncthreads();
    if (threadIdx.x == 0)
        partials[b] = fmaxf(fmaxf(red[0], red[1]), fmaxf(red[2], red[3]));
}

// ---------------- finalize: reduce partials -> scale (2 blocks) ----------------
__global__ void w8a8_finalize_kernel(const float* __restrict__ partials,
                                     float* __restrict__ finals) {
    int base = (blockIdx.x == 0) ? 0 : NB_X;
    int n    = (blockIdx.x == 0) ? NB_X : NB_W;
    float m = 0.f;
    for (int i = threadIdx.x; i < n; i += 256)
        m = fmaxf(m, partials[base + i]);
    #pragma unroll
    for (int o = 32; o > 0; o >>= 1)
        m = fmaxf(m, __shfl_xor(m, o, 64));
    __shared__ float red[4];
    if ((threadIdx.x & 63) == 0) red[threadIdx.x >> 6] = m;
    __syncthreads();
    if (threadIdx.x == 0) {
        m = fmaxf(fmaxf(red[0], red[1]), fmaxf(red[2], red[3]));
        finals[blockIdx.x] = fmaxf(m, 1e-5f) / 127.0f;   // scale
    }
}

// ---------------- quantize both tensors: q = rintf(v / scale) ----------------
__global__ void w8a8_quant_kernel(const float* __restrict__ x,
                                  const float* __restrict__ w,
                                  unsigned* __restrict__ qx,
                                  unsigned* __restrict__ qw,
                                  const float* __restrict__ finals) {
    int b = blockIdx.x;
    const float4* in4;
    unsigned* outq;
    int n4, bi, nb;
    float scale;
    if (b < NB_X) { in4 = (const float4*)x; outq = qx; n4 = (M_DIM * K_DIM) / 4; bi = b;        nb = NB_X; scale = finals[0]; }
    else          { in4 = (const float4*)w; outq = qw; n4 = (N_DIM * K_DIM) / 4; bi = b - NB_X; nb = NB_W; scale = finals[1]; }

    int stride = nb * 256;
    for (int i = bi * 256 + threadIdx.x; i < n4; i += stride) {
        float4 v = in4[i];
        int q0 = (int)rintf(v.x / scale);
        int q1 = (int)rintf(v.y / scale);
        int q2 = (int)rintf(v.z / scale);
        int q3 = (int)rintf(v.w / scale);
        outq[i] = (unsigned)(q0 & 0xff) | ((unsigned)(q1 & 0xff) << 8) |
                  ((unsigned)(q2 & 0xff) << 16) | ((unsigned)(q3 & 0xff) << 24);
    }
}

// ========== 256x256 i8 GEMM: double-buffer, 4 phases/K-tile, counted vmcnt(8) ==========
// 512 threads = 8 waves (2M x 4N). Per-wave C: 128x64 = acc[8][4] of i32x4.
// BK=128 i8 (128B rows). LDS: 2 x (A 32KB + B 32KB) = 128KB.
// A region mh (16KB): slots hold rows {mh0: 0-63,128-191 ; mh1: 64-127,192-255}
// B region nh (16KB): slots hold rows {nh0: rows r with r%64<32 ; nh1: +32}
// chunk-XOR swizzle (c ^= slot&7, 16B units) on global source + ds_read (both-sides).
// Schedule (race-proof): all reads of buf's region complete >=1 barrier before its re-stage;
// single vmcnt(8) per tile retires exactly the PREVIOUS tile's 8 stage-loads.
#define BM 256
#define BN 256
#define BK 128
#define NT (K_DIM / BK)      // 32 K-tiles
#define NTN (N_DIM / BN)     // 16
#define LDS_BUF 65536

#define STAGE_A(BUF, MH, KT) do {                                              \
    _Pragma("unroll")                                                          \
    for (int r_ = 0; r_ < 2; ++r_)                                             \
        __builtin_amdgcn_global_load_lds(                                      \
            (const __attribute__((address_space(1))) void*)(a_base + (size_t)((KT) + goffA[MH][r_])), \
            (__attribute__((address_space(3))) void*)(lds + (BUF)*LDS_BUF + (MH)*16384 + ldst[r_]),   \
            16, 0, 0);                                                         \
} while (0)

#define STAGE_B(BUF, NH, KT) do {                                              \
    _Pragma("unroll")                                                          \
    for (int r_ = 0; r_ < 2; ++r_)                                             \
        __builtin_amdgcn_global_load_lds(                                      \
            (const __attribute__((address_space(1))) void*)(b_base + (size_t)((KT) + goffB[NH][r_])), \
            (__attribute__((address_space(3))) void*)(lds + (BUF)*LDS_BUF + 32768 + (NH)*16384 + ldst[r_]), \
            16, 0, 0);                                                         \
} while (0)

#define LOAD_A(BUF, MH) do {                                                   \
    _Pragma("unroll")                                                          \
    for (int m4_ = 0; m4_ < 4; ++m4_) {                                        \
        aF[m4_][0] = *(const i32x4*)(lds + (BUF)*LDS_BUF + (MH)*16384 + laneA + m4_*2048 + koff[0]); \
        aF[m4_][1] = *(const i32x4*)(lds + (BUF)*LDS_BUF + (MH)*16384 + laneA + m4_*2048 + koff[1]); \
    }                                                                          \
} while (0)

#define LOAD_B(BUF, NH) do {                                                   \
    _Pragma("unroll")                                                          \
    for (int n1_ = 0; n1_ < 2; ++n1_) {                                        \
        bF[n1_][0] = *(const i32x4*)(lds + (BUF)*LDS_BUF + 32768 + (NH)*16384 + laneB + n1_*2048 + koff[0]); \
        bF[n1_][1] = *(const i32x4*)(lds + (BUF)*LDS_BUF + 32768 + (NH)*16384 + laneB + n1_*2048 + koff[1]); \
    }                                                                          \
} while (0)

#define MMA(MH, NH) do {                                                       \
    __builtin_amdgcn_s_setprio(1);                                             \
    _Pragma("unroll")                                                          \
    for (int m4_ = 0; m4_ < 4; ++m4_) {                                        \
        _Pragma("unroll")                                                      \
        for (int n1_ = 0; n1_ < 2; ++n1_) {                                    \
            i32x4 c_ = acc[(MH)*4 + m4_][(NH)*2 + n1_];                        \
            c_ = __builtin_amdgcn_mfma_i32_16x16x64_i8(aF[m4_][0], bF[n1_][0], c_, 0, 0, 0); \
            c_ = __builtin_amdgcn_mfma_i32_16x16x64_i8(aF[m4_][1], bF[n1_][1], c_, 0, 0, 0); \
            acc[(MH)*4 + m4_][(NH)*2 + n1_] = c_;                              \
        }                                                                      \
    }                                                                          \
    __builtin_amdgcn_s_setprio(0);                                             \
} while (0)

#define BAR() __builtin_amdgcn_s_barrier()
#define VMW8() asm volatile("s_waitcnt vmcnt(8)" ::: "memory")

// One K-tile: 4 compute phases reading buf; 8 stage-loads for K-tile (KT2) into the
// SAME buf, each issued >=1 barrier after its region's last read; then vmcnt(8)+BAR
// confirms the OTHER buffer (staged last tile) before the next tile reads it.
#define TILE_BODY(BUF, KT2) do {                                               \
    LOAD_A(BUF, 0); LOAD_B(BUF, 0);       /* P1: (mh0,nh0) */                  \
    BAR(); MMA(0, 0); BAR();                                                   \
    LOAD_A(BUF, 1);                       /* P2: (mh1,nh0) */                  \
    BAR(); MMA(1, 0); BAR();                                                   \
    LOAD_B(BUF, 1);                       /* P3: (mh1,nh1) */                  \
    STAGE_B(BUF, 0, KT2);                 /* B.nh0 last read P1 */             \
    BAR(); MMA(1, 1); BAR();                                                   \
    LOAD_A(BUF, 0);                       /* P4: (mh0,nh1) */                  \
    STAGE_A(BUF, 1, KT2);                 /* A.mh1 last read P2 */             \
    STAGE_B(BUF, 1, KT2);                 /* B.nh1 last read P3 */             \
    BAR(); MMA(0, 1); BAR();                                                   \
    STAGE_A(BUF, 0, KT2);                 /* A.mh0 last read P4 */             \
    VMW8();                               /* retire other-buf's 8 stages */    \
    BAR();                                                                     \
} while (0)

__global__ __launch_bounds__(512, 2) void w8a8_gemm_kernel(
    const signed char* __restrict__ qa,   // [M, K]
    const signed char* __restrict__ qb,   // [N, K]
    const float* __restrict__ bias,       // [N]
    const float* __restrict__ finals,     // {scale_x, scale_w}
    float* __restrict__ out)              // [M, N]
{
    __shared__ __align__(16) char lds[2 * LDS_BUF];

    int t    = threadIdx.x;      // 0..511
    int lane = t & 63;
    int wid  = t >> 6;           // 0..7
    int wm   = wid >> 2;         // 0..1
    int wn   = wid & 3;          // 0..3
    int fr   = lane & 15;
    int fg   = lane >> 4;        // 0..3
    int frb2 = (fr >> 2) & 1;

    int bid = blockIdx.x;
    int cpx = gridDim.x >> 3;    // 64 (512 blocks % 8 == 0, bijective)
    int swz = (bid & 7) * cpx + (bid >> 3);
    int tm = swz / NTN;          // 0..31
    int tn = swz % NTN;          // 0..15

    const signed char* a_base = qa + (size_t)tm * BM * K_DIM;
    const signed char* b_base = qb + (size_t)tn * BN * K_DIM;

    // ---- staging precompute (per-thread constants across K) ----
    int goffA[2][2], goffB[2][2], ldst[2];
    #pragma unroll
    for (int r = 0; r < 2; ++r) {
        int unit = r * 512 + t;          // 0..1023
        int sl   = unit >> 3;            // 0..127
        int c    = unit & 7;
        int cs   = c ^ (sl & 7);         // inverse swizzle on global source
        int rowA = (sl & 63) + ((sl >> 6) & 1) * 128;
        goffA[0][r] = rowA * K_DIM + cs * 16;
        goffA[1][r] = (rowA + 64) * K_DIM + cs * 16;
        int rowB = ((sl >> 5) & 3) * 64 + (sl & 31);
        goffB[0][r] = rowB * K_DIM + cs * 16;
        goffB[1][r] = (rowB + 32) * K_DIM + cs * 16;
        ldst[r] = r * 8192 + t * 16;
    }

    // ---- read-side lane bases (swizzled) ----
    int laneA = (wm * 64 + fr) * 128 + (fg ^ (fr & 3)) * 16;
    int laneB = (wn * 32 + fr) * 128 + (fg ^ (fr & 3)) * 16;
    int koff[2];
    koff[0] = frb2 * 64;          // swizzled location of k-half 0 (bit2 ^= frb2)
    koff[1] = 64 - frb2 * 64;     // swizzled location of k-half 1

    i32x4 acc[8][4] = {};
    i32x4 aF[4][2], bF[2][2];

    // ---- prologue: stage K-tile 0 -> buf0, K-tile 1 -> buf1; confirm buf0 ----
    STAGE_A(0, 0, 0);  STAGE_A(0, 1, 0);  STAGE_B(0, 0, 0);  STAGE_B(0, 1, 0);
    STAGE_A(1, 0, BK); STAGE_A(1, 1, BK); STAGE_B(1, 0, BK); STAGE_B(1, 1, BK);
    VMW8();            // retire buf0's 8, keep buf1's 8 in flight
    BAR();

    // ---- main loop: 16 iterations x 2 K-tiles ----
    #pragma unroll 1
    for (int it = 0; it < NT / 2; ++it) {
        int kt2 = ((2 * it + 2) & (NT - 1)) * BK;   // wraps at end: garbage stage, never read
        int kt3 = ((2 * it + 3) & (NT - 1)) * BK;
        TILE_BODY(0, kt2);
        TILE_BODY(1, kt3);
    }
    asm volatile("s_waitcnt vmcnt(0)" ::: "memory");   // drain wrapped garbage stages
    BAR();

    // ---- epilogue: dequant + bias; C/D map col=fr, row=fg*4+rr ----
    float sprod = finals[0] * finals[1];
    int orow0 = tm * BM + wm * 128 + fg * 4;
    int ocol0 = tn * BN + wn * 64 + fr;
    #pragma unroll
    for (int n = 0; n < 4; ++n) {
        int col = ocol0 + n * 16;
        float bv = bias[col];
        #pragma unroll
        for (int m = 0; m < 8; ++m) {
            int row = orow0 + m * 16;
            #pragma unroll
            for (int rr = 0; rr < 4; ++rr) {
                out[(size_t)(row + rr) * N_DIM + col] = (float)acc[m][n][rr] * sprod + bv;
            }
        }
    }
}

extern "C" void kernel_launch(void* const* d_in, const int* in_sizes, int n_in,
                              void* d_out, int out_size, void* d_ws, size_t ws_size,
                              hipStream_t stream) {
    const float* x    = (const float*)d_in[0];   // [8192, 4096]
    const float* wgt  = (const float*)d_in[1];   // [4096, 4096]
    const float* bias = (const float*)d_in[2];   // [4096]
    float* out = (float*)d_out;

    char* ws = (char*)d_ws;
    float* finals   = (float*)ws;
    float* partials = (float*)(ws + 256);
    signed char* qx = (signed char*)(ws + 16384);
    signed char* qw = qx + (size_t)M_DIM * K_DIM;

    w8a8_absmax_kernel<<<NB_TOT, 256, 0, stream>>>(x, wgt, partials);
    w8a8_finalize_kernel<<<2, 256, 0, stream>>>(partials, finals);
    w8a8_quant_kernel<<<NB_TOT, 256, 0, stream>>>(x, wgt, (unsigned*)qx, (unsigned*)qw, finals);
    w8a8_gemm_kernel<<<(M_DIM / BM) * (N_DIM / BN), 512, 0, stream>>>(qx, qw, bias, finals, out);
}

// Round 5
// 222.031 us; speedup vs baseline: 1.6873x; 1.0197x over previous
//
#include <hip/hip_runtime.h>
#include <hip/hip_bf16.h>
#include <stdint.h>

#define M_DIM 8192
#define N_DIM 4096
#define K_DIM 4096

typedef int i32x4 __attribute__((ext_vector_type(4)));

#define NB_X 2048
#define NB_W 1024
#define NB_TOT (NB_X + NB_W)

// ---------------- absmax: per-block partial max, no atomics ----------------
__global__ void w8a8_absmax_kernel(const float* __restrict__ x,
                                   const float* __restrict__ w,
                                   float* __restrict__ partials) {
    int b = blockIdx.x;
    const float4* p;
    int n4, bi, nb;
    if (b < NB_X) { p = (const float4*)x; n4 = (M_DIM * K_DIM) / 4; bi = b;        nb = NB_X; }
    else          { p = (const float4*)w; n4 = (N_DIM * K_DIM) / 4; bi = b - NB_X; nb = NB_W; }

    float m = 0.f;
    int stride = nb * 256;
    for (int i = bi * 256 + threadIdx.x; i < n4; i += stride) {
        float4 v = p[i];
        m = fmaxf(m, fmaxf(fmaxf(fabsf(v.x), fabsf(v.y)), fmaxf(fabsf(v.z), fabsf(v.w))));
    }
    #pragma unroll
    for (int o = 32; o > 0; o >>= 1)
        m = fmaxf(m, __shfl_xor(m, o, 64));

    __shared__ float red[4];
    if ((threadIdx.x & 63) == 0) red[threadIdx.x >> 6] = m;
    __syncthreads();
    if (threadIdx.x == 0)
        partials[b] = fmaxf(fmaxf(red[0], red[1]), fmaxf(red[2], red[3]));
}

// ---------------- finalize: reduce partials -> scale (2 blocks) ----------------
__global__ void w8a8_finalize_kernel(const float* __restrict__ partials,
                                     float* __restrict__ finals) {
    int base = (blockIdx.x == 0) ? 0 : NB_X;
    int n    = (blockIdx.x == 0) ? NB_X : NB_W;
    float m = 0.f;
    for (int i = threadIdx.x; i < n; i += 256)
        m = fmaxf(m, partials[base + i]);
    #pragma unroll
    for (int o = 32; o > 0; o >>= 1)
        m = fmaxf(m, __shfl_xor(m, o, 64));
    __shared__ float red[4];
    if ((threadIdx.x & 63) == 0) red[threadIdx.x >> 6] = m;
    __syncthreads();
    if (threadIdx.x == 0) {
        m = fmaxf(fmaxf(red[0], red[1]), fmaxf(red[2], red[3]));
        finals[blockIdx.x] = fmaxf(m, 1e-5f) / 127.0f;   // scale
    }
}

// ---------------- quantize both tensors: q = rintf(v / scale) ----------------
__global__ void w8a8_quant_kernel(const float* __restrict__ x,
                                  const float* __restrict__ w,
                                  unsigned* __restrict__ qx,
                                  unsigned* __restrict__ qw,
                                  const float* __restrict__ finals) {
    int b = blockIdx.x;
    const float4* in4;
    unsigned* outq;
    int n4, bi, nb;
    float scale;
    if (b < NB_X) { in4 = (const float4*)x; outq = qx; n4 = (M_DIM * K_DIM) / 4; bi = b;        nb = NB_X; scale = finals[0]; }
    else          { in4 = (const float4*)w; outq = qw; n4 = (N_DIM * K_DIM) / 4; bi = b - NB_X; nb = NB_W; scale = finals[1]; }

    int stride = nb * 256;
    for (int i = bi * 256 + threadIdx.x; i < n4; i += stride) {
        float4 v = in4[i];
        int q0 = (int)rintf(v.x / scale);
        int q1 = (int)rintf(v.y / scale);
        int q2 = (int)rintf(v.z / scale);
        int q3 = (int)rintf(v.w / scale);
        outq[i] = (unsigned)(q0 & 0xff) | ((unsigned)(q1 & 0xff) << 8) |
                  ((unsigned)(q2 & 0xff) << 16) | ((unsigned)(q3 & 0xff) << 24);
    }
}

// ========== 256x256 i8 GEMM: double-buffer, 4 phases/K-tile, counted vmcnt(8) ==========
// 512 threads = 8 waves (2M x 4N). Per-wave C: 128x64 = acc[8][4] of i32x4.
// BK=128 i8 (128B rows). LDS: 2 x (A 32KB + B 32KB) = 128KB.
// Quadrant walk (00 -> 01 -> 11 -> 10): re-loads B (4 reads) not A (8) -> 28 b128/tile/wave.
// Region retirement: A.mh0 after P1, B.nh1 after P2, A.mh1 after P3, B.nh0 after P4;
// each region staged >=1 barrier after its last read. Single vmcnt(8)/tile retires the
// OTHER buffer's 8 stage-loads. Explicit lgkmcnt(0)+sched_barrier(0) before each MFMA
// cluster (m201 discipline, rule #18).
#define BM 256
#define BN 256
#define BK 128
#define NT (K_DIM / BK)      // 32 K-tiles
#define NTN (N_DIM / BN)     // 16
#define LDS_BUF 65536

#define STAGE_A(BUF, MH, KT) do {                                              \
    _Pragma("unroll")                                                          \
    for (int r_ = 0; r_ < 2; ++r_)                                             \
        __builtin_amdgcn_global_load_lds(                                      \
            (const __attribute__((address_space(1))) void*)(a_base + (size_t)((KT) + goffA[MH][r_])), \
            (__attribute__((address_space(3))) void*)(lds + (BUF)*LDS_BUF + (MH)*16384 + ldst[r_]),   \
            16, 0, 0);                                                         \
} while (0)

#define STAGE_B(BUF, NH, KT) do {                                              \
    _Pragma("unroll")                                                          \
    for (int r_ = 0; r_ < 2; ++r_)                                             \
        __builtin_amdgcn_global_load_lds(                                      \
            (const __attribute__((address_space(1))) void*)(b_base + (size_t)((KT) + goffB[NH][r_])), \
            (__attribute__((address_space(3))) void*)(lds + (BUF)*LDS_BUF + 32768 + (NH)*16384 + ldst[r_]), \
            16, 0, 0);                                                         \
} while (0)

#define LOAD_A(BUF, MH) do {                                                   \
    _Pragma("unroll")                                                          \
    for (int m4_ = 0; m4_ < 4; ++m4_) {                                        \
        aF[m4_][0] = *(const i32x4*)(lds + (BUF)*LDS_BUF + (MH)*16384 + laneA + m4_*2048 + koff[0]); \
        aF[m4_][1] = *(const i32x4*)(lds + (BUF)*LDS_BUF + (MH)*16384 + laneA + m4_*2048 + koff[1]); \
    }                                                                          \
} while (0)

#define LOAD_B(BUF, NH) do {                                                   \
    _Pragma("unroll")                                                          \
    for (int n1_ = 0; n1_ < 2; ++n1_) {                                        \
        bF[n1_][0] = *(const i32x4*)(lds + (BUF)*LDS_BUF + 32768 + (NH)*16384 + laneB + n1_*2048 + koff[0]); \
        bF[n1_][1] = *(const i32x4*)(lds + (BUF)*LDS_BUF + 32768 + (NH)*16384 + laneB + n1_*2048 + koff[1]); \
    }                                                                          \
} while (0)

#define MMA(MH, NH) do {                                                       \
    __builtin_amdgcn_s_setprio(1);                                             \
    _Pragma("unroll")                                                          \
    for (int m4_ = 0; m4_ < 4; ++m4_) {                                        \
        _Pragma("unroll")                                                      \
        for (int n1_ = 0; n1_ < 2; ++n1_) {                                    \
            i32x4 c_ = acc[(MH)*4 + m4_][(NH)*2 + n1_];                        \
            c_ = __builtin_amdgcn_mfma_i32_16x16x64_i8(aF[m4_][0], bF[n1_][0], c_, 0, 0, 0); \
            c_ = __builtin_amdgcn_mfma_i32_16x16x64_i8(aF[m4_][1], bF[n1_][1], c_, 0, 0, 0); \
            acc[(MH)*4 + m4_][(NH)*2 + n1_] = c_;                              \
        }                                                                      \
    }                                                                          \
    __builtin_amdgcn_s_setprio(0);                                             \
} while (0)

#define BAR() __builtin_amdgcn_s_barrier()
#define VMW8() asm volatile("s_waitcnt vmcnt(8)" ::: "memory")
#define LGKM0() do {                                                           \
    asm volatile("s_waitcnt lgkmcnt(0)" ::: "memory");                         \
    __builtin_amdgcn_sched_barrier(0);                                         \
} while (0)

// One K-tile: 4 compute phases reading BUF; 8 stage-loads for K-tile KT2 into the SAME
// buf, each issued >=1 barrier after its region's last read; then vmcnt(8)+BAR confirms
// the OTHER buffer (staged last tile) before the next tile reads it.
#define TILE_BODY(BUF, KT2) do {                                               \
    LOAD_A(BUF, 0); LOAD_B(BUF, 0);       /* P1: (mh0,nh0) */                  \
    BAR(); LGKM0(); MMA(0, 0); BAR();                                          \
    LOAD_B(BUF, 1);                       /* P2: (mh0,nh1) */                  \
    STAGE_A(BUF, 0, KT2);                 /* A.mh0 last read P1 */             \
    BAR(); LGKM0(); MMA(0, 1); BAR();                                          \
    LOAD_A(BUF, 1);                       /* P3: (mh1,nh1) */                  \
    STAGE_B(BUF, 1, KT2);                 /* B.nh1 last read P2 */             \
    BAR(); LGKM0(); MMA(1, 1); BAR();                                          \
    LOAD_B(BUF, 0);                       /* P4: (mh1,nh0) re-read B.nh0 */    \
    STAGE_A(BUF, 1, KT2);                 /* A.mh1 last read P3 */             \
    BAR(); LGKM0(); MMA(1, 0); BAR();                                          \
    STAGE_B(BUF, 0, KT2);                 /* B.nh0 last read P4 */             \
    VMW8();                               /* retire other-buf's 8 stages */    \
    BAR();                                                                     \
} while (0)

__global__ __launch_bounds__(512, 2) void w8a8_gemm_kernel(
    const signed char* __restrict__ qa,   // [M, K]
    const signed char* __restrict__ qb,   // [N, K]
    const float* __restrict__ bias,       // [N]
    const float* __restrict__ finals,     // {scale_x, scale_w}
    float* __restrict__ out)              // [M, N]
{
    __shared__ __align__(16) char lds[2 * LDS_BUF];

    int t    = threadIdx.x;      // 0..511
    int lane = t & 63;
    int wid  = t >> 6;           // 0..7
    int wm   = wid >> 2;         // 0..1
    int wn   = wid & 3;          // 0..3
    int fr   = lane & 15;
    int fg   = lane >> 4;        // 0..3
    int frb2 = (fr >> 2) & 1;

    int bid = blockIdx.x;
    int cpx = gridDim.x >> 3;    // 64 (512 blocks % 8 == 0, bijective)
    int swz = (bid & 7) * cpx + (bid >> 3);
    int tm = swz / NTN;          // 0..31
    int tn = swz % NTN;          // 0..15

    const signed char* a_base = qa + (size_t)tm * BM * K_DIM;
    const signed char* b_base = qb + (size_t)tn * BN * K_DIM;

    // ---- staging precompute (per-thread constants across K) ----
    int goffA[2][2], goffB[2][2], ldst[2];
    #pragma unroll
    for (int r = 0; r < 2; ++r) {
        int unit = r * 512 + t;          // 0..1023
        int sl   = unit >> 3;            // 0..127
        int c    = unit & 7;
        int cs   = c ^ (sl & 7);         // inverse swizzle on global source
        int rowA = (sl & 63) + ((sl >> 6) & 1) * 128;
        goffA[0][r] = rowA * K_DIM + cs * 16;
        goffA[1][r] = (rowA + 64) * K_DIM + cs * 16;
        int rowB = ((sl >> 5) & 3) * 64 + (sl & 31);
        goffB[0][r] = rowB * K_DIM + cs * 16;
        goffB[1][r] = (rowB + 32) * K_DIM + cs * 16;
        ldst[r] = r * 8192 + t * 16;
    }

    // ---- read-side lane bases (swizzled) ----
    int laneA = (wm * 64 + fr) * 128 + (fg ^ (fr & 3)) * 16;
    int laneB = (wn * 32 + fr) * 128 + (fg ^ (fr & 3)) * 16;
    int koff[2];
    koff[0] = frb2 * 64;          // swizzled location of k-half 0 (bit2 ^= frb2)
    koff[1] = 64 - frb2 * 64;     // swizzled location of k-half 1

    i32x4 acc[8][4] = {};
    i32x4 aF[4][2], bF[2][2];

    // ---- prologue: stage K-tile 0 -> buf0, K-tile 1 -> buf1; confirm buf0 ----
    STAGE_A(0, 0, 0);  STAGE_A(0, 1, 0);  STAGE_B(0, 0, 0);  STAGE_B(0, 1, 0);
    STAGE_A(1, 0, BK); STAGE_A(1, 1, BK); STAGE_B(1, 0, BK); STAGE_B(1, 1, BK);
    VMW8();            // retire buf0's 8, keep buf1's 8 in flight
    BAR();

    // ---- main loop: 16 iterations x 2 K-tiles ----
    #pragma unroll 1
    for (int it = 0; it < NT / 2; ++it) {
        int kt2 = ((2 * it + 2) & (NT - 1)) * BK;   // wraps at end: garbage stage, never read
        int kt3 = ((2 * it + 3) & (NT - 1)) * BK;
        TILE_BODY(0, kt2);
        TILE_BODY(1, kt3);
    }
    asm volatile("s_waitcnt vmcnt(0)" ::: "memory");   // drain wrapped garbage stages
    BAR();

    // ---- epilogue: dequant + bias; C/D map col=fr, row=fg*4+rr ----
    float sprod = finals[0] * finals[1];
    int orow0 = tm * BM + wm * 128 + fg * 4;
    int ocol0 = tn * BN + wn * 64 + fr;
    #pragma unroll
    for (int n = 0; n < 4; ++n) {
        int col = ocol0 + n * 16;
        float bv = bias[col];
        #pragma unroll
        for (int m = 0; m < 8; ++m) {
            int row = orow0 + m * 16;
            #pragma unroll
            for (int rr = 0; rr < 4; ++rr) {
                out[(size_t)(row + rr) * N_DIM + col] = (float)acc[m][n][rr] * sprod + bv;
            }
        }
    }
}

extern "C" void kernel_launch(void* const* d_in, const int* in_sizes, int n_in,
                              void* d_out, int out_size, void* d_ws, size_t ws_size,
                              hipStream_t stream) {
    const float* x    = (const float*)d_in[0];   // [8192, 4096]
    const float* wgt  = (const float*)d_in[1];   // [4096, 4096]
    const float* bias = (const float*)d_in[2];   // [4096]
    float* out = (float*)d_out;

    char* ws = (char*)d_ws;
    float* finals   = (float*)ws;
    float* partials = (float*)(ws + 256);
    signed char* qx = (signed char*)(ws + 16384);
    signed char* qw = qx + (size_t)M_DIM * K_DIM;

    w8a8_absmax_kernel<<<NB_TOT, 256, 0, stream>>>(x, wgt, partials);
    w8a8_finalize_kernel<<<2, 256, 0, stream>>>(partials, finals);
    w8a8_quant_kernel<<<NB_TOT, 256, 0, stream>>>(x, wgt, (unsigned*)qx, (unsigned*)qw, finals);
    w8a8_gemm_kernel<<<(M_DIM / BM) * (N_DIM / BN), 512, 0, stream>>>(qx, qw, bias, finals, out);
}

// Round 6
// 217.873 us; speedup vs baseline: 1.7195x; 1.0191x over previous
//
#include <hip/hip_runtime.h>
#include <hip/hip_bf16.h>
#include <stdint.h>

#define M_DIM 8192
#define N_DIM 4096
#define K_DIM 4096

typedef int i32x4 __attribute__((ext_vector_type(4)));

#define NB_X 2048
#define NB_W 1024
#define NB_TOT (NB_X + NB_W)

// ---------------- absmax: per-block partial max, no atomics ----------------
__global__ void w8a8_absmax_kernel(const float* __restrict__ x,
                                   const float* __restrict__ w,
                                   float* __restrict__ partials) {
    int b = blockIdx.x;
    const float4* p;
    int n4, bi, nb;
    if (b < NB_X) { p = (const float4*)x; n4 = (M_DIM * K_DIM) / 4; bi = b;        nb = NB_X; }
    else          { p = (const float4*)w; n4 = (N_DIM * K_DIM) / 4; bi = b - NB_X; nb = NB_W; }

    float m = 0.f;
    int stride = nb * 256;
    for (int i = bi * 256 + threadIdx.x; i < n4; i += stride) {
        float4 v = p[i];
        m = fmaxf(m, fmaxf(fmaxf(fabsf(v.x), fabsf(v.y)), fmaxf(fabsf(v.z), fabsf(v.w))));
    }
    #pragma unroll
    for (int o = 32; o > 0; o >>= 1)
        m = fmaxf(m, __shfl_xor(m, o, 64));

    __shared__ float red[4];
    if ((threadIdx.x & 63) == 0) red[threadIdx.x >> 6] = m;
    __syncthreads();
    if (threadIdx.x == 0)
        partials[b] = fmaxf(fmaxf(red[0], red[1]), fmaxf(red[2], red[3]));
}

// ---------------- finalize: reduce partials -> scale (2 blocks) ----------------
__global__ void w8a8_finalize_kernel(const float* __restrict__ partials,
                                     float* __restrict__ finals) {
    int base = (blockIdx.x == 0) ? 0 : NB_X;
    int n    = (blockIdx.x == 0) ? NB_X : NB_W;
    float m = 0.f;
    for (int i = threadIdx.x; i < n; i += 256)
        m = fmaxf(m, partials[base + i]);
    #pragma unroll
    for (int o = 32; o > 0; o >>= 1)
        m = fmaxf(m, __shfl_xor(m, o, 64));
    __shared__ float red[4];
    if ((threadIdx.x & 63) == 0) red[threadIdx.x >> 6] = m;
    __syncthreads();
    if (threadIdx.x == 0) {
        m = fmaxf(fmaxf(red[0], red[1]), fmaxf(red[2], red[3]));
        finals[blockIdx.x] = fmaxf(m, 1e-5f) / 127.0f;   // scale
    }
}

// ---------------- quantize both tensors: q = rintf(v / scale) ----------------
__global__ void w8a8_quant_kernel(const float* __restrict__ x,
                                  const float* __restrict__ w,
                                  unsigned* __restrict__ qx,
                                  unsigned* __restrict__ qw,
                                  const float* __restrict__ finals) {
    int b = blockIdx.x;
    const float4* in4;
    unsigned* outq;
    int n4, bi, nb;
    float scale;
    if (b < NB_X) { in4 = (const float4*)x; outq = qx; n4 = (M_DIM * K_DIM) / 4; bi = b;        nb = NB_X; scale = finals[0]; }
    else          { in4 = (const float4*)w; outq = qw; n4 = (N_DIM * K_DIM) / 4; bi = b - NB_X; nb = NB_W; scale = finals[1]; }

    int stride = nb * 256;
    for (int i = bi * 256 + threadIdx.x; i < n4; i += stride) {
        float4 v = in4[i];
        int q0 = (int)rintf(v.x / scale);
        int q1 = (int)rintf(v.y / scale);
        int q2 = (int)rintf(v.z / scale);
        int q3 = (int)rintf(v.w / scale);
        outq[i] = (unsigned)(q0 & 0xff) | ((unsigned)(q1 & 0xff) << 8) |
                  ((unsigned)(q2 & 0xff) << 16) | ((unsigned)(q3 & 0xff) << 24);
    }
}

// ========== 256x256 i8 GEMM: dbuf + cross-phase register read-ahead pipeline ==========
// 512 threads = 8 waves (2M x 4N). Per-wave C: 128x64 = acc[8][4] of i32x4.
// BK=128 i8. LDS: 2 x 64KB. Quadrant walk P1(0,0) P2(0,1) P3(1,1) P4(1,0); B0 persists
// in regs across the tile (ping-pong across tile parity).
// Pipeline: each phase issues the NEXT phase's ds_reads before its MFMA cluster; counted
// lgkmcnt waits only for last phase's reads -> LDS pipe streams under MFMA.
// Drain ledger (all reads drained >=1 barrier before their region's re-stage):
//   B1 read P1 -> drained P2 lgkm(8)  -> B.nh1 staged P3
//   A1 read P2 -> drained P3 lgkm(0)  -> A.mh1 staged P4
//   A0,B0 read P4 (other buf, after vmcnt(6)+BAR) -> drained P1 lgkm(4)
//       -> A.mh0,B.nh0 staged next-body P2
// vmcnt ledger: entry 8 outstanding (next tile); +4 (P2) +2 (P3); vmcnt(6) at P4 retires
// exactly prev tile's 8; +2 (P4 stage) -> exit 8.
#define BM 256
#define BN 256
#define BK 128
#define NT (K_DIM / BK)      // 32 K-tiles
#define NTN (N_DIM / BN)     // 16
#define LDS_BUF 65536

#define STAGE_A(BUF, MH, KT) do {                                              \
    _Pragma("unroll")                                                          \
    for (int r_ = 0; r_ < 2; ++r_)                                             \
        __builtin_amdgcn_global_load_lds(                                      \
            (const __attribute__((address_space(1))) void*)(a_base + (size_t)((KT) + goffA[MH][r_])), \
            (__attribute__((address_space(3))) void*)(lds + (BUF)*LDS_BUF + (MH)*16384 + ldst[r_]),   \
            16, 0, 0);                                                         \
} while (0)

#define STAGE_B(BUF, NH, KT) do {                                              \
    _Pragma("unroll")                                                          \
    for (int r_ = 0; r_ < 2; ++r_)                                             \
        __builtin_amdgcn_global_load_lds(                                      \
            (const __attribute__((address_space(1))) void*)(b_base + (size_t)((KT) + goffB[NH][r_])), \
            (__attribute__((address_space(3))) void*)(lds + (BUF)*LDS_BUF + 32768 + (NH)*16384 + ldst[r_]), \
            16, 0, 0);                                                         \
} while (0)

// read A.mh frags (8 x ds_read_b128) into DST[4][2]
#define RA_A(BUF, MH, DST) do {                                                \
    _Pragma("unroll")                                                          \
    for (int m4_ = 0; m4_ < 4; ++m4_) {                                        \
        DST[m4_][0] = *(const i32x4*)(lds + (BUF)*LDS_BUF + (MH)*16384 + laneA + m4_*2048 + koff[0]); \
        DST[m4_][1] = *(const i32x4*)(lds + (BUF)*LDS_BUF + (MH)*16384 + laneA + m4_*2048 + koff[1]); \
    }                                                                          \
} while (0)

// read B.nh frags (4 x ds_read_b128) into DST[2][2]
#define RA_B(BUF, NH, DST) do {                                                \
    _Pragma("unroll")                                                          \
    for (int n1_ = 0; n1_ < 2; ++n1_) {                                        \
        DST[n1_][0] = *(const i32x4*)(lds + (BUF)*LDS_BUF + 32768 + (NH)*16384 + laneB + n1_*2048 + koff[0]); \
        DST[n1_][1] = *(const i32x4*)(lds + (BUF)*LDS_BUF + 32768 + (NH)*16384 + laneB + n1_*2048 + koff[1]); \
    }                                                                          \
} while (0)

#define MMA4(MH, NH, AARR, BARR) do {                                          \
    __builtin_amdgcn_s_setprio(1);                                             \
    _Pragma("unroll")                                                          \
    for (int m4_ = 0; m4_ < 4; ++m4_) {                                        \
        _Pragma("unroll")                                                      \
        for (int n1_ = 0; n1_ < 2; ++n1_) {                                    \
            i32x4 c_ = acc[(MH)*4 + m4_][(NH)*2 + n1_];                        \
            c_ = __builtin_amdgcn_mfma_i32_16x16x64_i8(AARR[m4_][0], BARR[n1_][0], c_, 0, 0, 0); \
            c_ = __builtin_amdgcn_mfma_i32_16x16x64_i8(AARR[m4_][1], BARR[n1_][1], c_, 0, 0, 0); \
            acc[(MH)*4 + m4_][(NH)*2 + n1_] = c_;                              \
        }                                                                      \
    }                                                                          \
    __builtin_amdgcn_s_setprio(0);                                             \
} while (0)

#define BAR() __builtin_amdgcn_s_barrier()
#define SB0() __builtin_amdgcn_sched_barrier(0)
#define VMW(N) asm volatile("s_waitcnt vmcnt(" #N ")" ::: "memory")
#define LGKM(N) asm volatile("s_waitcnt lgkmcnt(" #N ")" ::: "memory")

// One K-tile, 4 phases. BUF = buffer being read, OBUF = other buffer (next tile).
// B0C = this tile's resident B.nh0 frags; B0N = next tile's (filled in P4).
#define TILE_BODY(BUF, OBUF, KT2, B0C, B0N) do {                               \
    /* P1: MMA(0,0); read-ahead B1 */                                          \
    RA_B(BUF, 1, bB1);                                                         \
    SB0(); LGKM(4); SB0();          /* A0,B0 (12 oldest) done */               \
    MMA4(0, 0, aA0, B0C);                                                      \
    BAR();                                                                     \
    /* P2: MMA(0,1); read-ahead A1; stage A.mh0+B.nh0 (read-finished prev P4) */ \
    STAGE_A(BUF, 0, KT2); STAGE_B(BUF, 0, KT2);                                \
    RA_A(BUF, 1, aA1);                                                         \
    SB0(); LGKM(8); SB0();          /* B1 (4 oldest) done */                   \
    MMA4(0, 1, aA0, bB1);                                                      \
    BAR();                                                                     \
    /* P3: MMA(1,1); stage B.nh1 (read-finished P1, drained P2) */             \
    STAGE_B(BUF, 1, KT2);                                                      \
    SB0(); LGKM(0); SB0();          /* A1 done */                              \
    MMA4(1, 1, aA1, bB1);                                                      \
    BAR();                                                                     \
    /* P4: confirm other buf; read-ahead next tile's A0,B0; stage A.mh1; MMA(1,0) */ \
    VMW(6);                         /* retire prev tile's 8 stages (own) */    \
    BAR();                          /* all waves retired -> OBUF valid */      \
    RA_A(OBUF, 0, aA0); RA_B(OBUF, 0, B0N);                                    \
    STAGE_A(BUF, 1, KT2);                                                      \
    SB0();                          /* pin read-ahead above MMA */             \
    MMA4(1, 0, aA1, B0C);                                                      \
    BAR();                                                                     \
} while (0)

__global__ __launch_bounds__(512, 1) void w8a8_gemm_kernel(
    const signed char* __restrict__ qa,   // [M, K]
    const signed char* __restrict__ qb,   // [N, K]
    const float* __restrict__ bias,       // [N]
    const float* __restrict__ finals,     // {scale_x, scale_w}
    float* __restrict__ out)              // [M, N]
{
    __shared__ __align__(16) char lds[2 * LDS_BUF];

    int t    = threadIdx.x;      // 0..511
    int lane = t & 63;
    int wid  = t >> 6;           // 0..7
    int wm   = wid >> 2;         // 0..1
    int wn   = wid & 3;          // 0..3
    int fr   = lane & 15;
    int fg   = lane >> 4;        // 0..3
    int frb2 = (fr >> 2) & 1;

    int bid = blockIdx.x;
    int cpx = gridDim.x >> 3;    // 64 (512 blocks % 8 == 0, bijective)
    int swz = (bid & 7) * cpx + (bid >> 3);
    int tm = swz / NTN;          // 0..31
    int tn = swz % NTN;          // 0..15

    const signed char* a_base = qa + (size_t)tm * BM * K_DIM;
    const signed char* b_base = qb + (size_t)tn * BN * K_DIM;

    // ---- staging precompute (per-thread constants across K) ----
    int goffA[2][2], goffB[2][2], ldst[2];
    #pragma unroll
    for (int r = 0; r < 2; ++r) {
        int unit = r * 512 + t;          // 0..1023
        int sl   = unit >> 3;            // 0..127
        int c    = unit & 7;
        int cs   = c ^ (sl & 7);         // inverse swizzle on global source
        int rowA = (sl & 63) + ((sl >> 6) & 1) * 128;
        goffA[0][r] = rowA * K_DIM + cs * 16;
        goffA[1][r] = (rowA + 64) * K_DIM + cs * 16;
        int rowB = ((sl >> 5) & 3) * 64 + (sl & 31);
        goffB[0][r] = rowB * K_DIM + cs * 16;
        goffB[1][r] = (rowB + 32) * K_DIM + cs * 16;
        ldst[r] = r * 8192 + t * 16;
    }

    // ---- read-side lane bases (swizzled) ----
    int laneA = (wm * 64 + fr) * 128 + (fg ^ (fr & 3)) * 16;
    int laneB = (wn * 32 + fr) * 128 + (fg ^ (fr & 3)) * 16;
    int koff[2];
    koff[0] = frb2 * 64;          // swizzled location of k-half 0
    koff[1] = 64 - frb2 * 64;     // swizzled location of k-half 1

    i32x4 acc[8][4] = {};
    i32x4 aA0[4][2], aA1[4][2], bB1[2][2], bB0a[2][2], bB0b[2][2];

    // ---- prologue: stage tile0 -> buf0, tile1 -> buf1; confirm buf0; preread P1 frags ----
    STAGE_A(0, 0, 0);  STAGE_A(0, 1, 0);  STAGE_B(0, 0, 0);  STAGE_B(0, 1, 0);
    STAGE_A(1, 0, BK); STAGE_A(1, 1, BK); STAGE_B(1, 0, BK); STAGE_B(1, 1, BK);
    VMW(8);            // retire tile0's 8 (own); tile1's 8 in flight
    BAR();             // all waves -> buf0 valid
    RA_A(0, 0, aA0); RA_B(0, 0, bB0a);   // 12 pending lgkm entering loop (steady state)

    // ---- main loop: 16 iterations x 2 K-tiles ----
    #pragma unroll 1
    for (int it = 0; it < NT / 2; ++it) {
        int kt2 = ((2 * it + 2) & (NT - 1)) * BK;   // wraps at end: garbage stage, never read
        int kt3 = ((2 * it + 3) & (NT - 1)) * BK;
        TILE_BODY(0, 1, kt2, bB0a, bB0b);
        TILE_BODY(1, 0, kt3, bB0b, bB0a);
    }
    asm volatile("s_waitcnt vmcnt(0) lgkmcnt(0)" ::: "memory");   // drain wrapped garbage
    BAR();

    // ---- epilogue: dequant + bias; C/D map col=fr, row=fg*4+rr ----
    float sprod = finals[0] * finals[1];
    int orow0 = tm * BM + wm * 128 + fg * 4;
    int ocol0 = tn * BN + wn * 64 + fr;
    #pragma unroll
    for (int n = 0; n < 4; ++n) {
        int col = ocol0 + n * 16;
        float bv = bias[col];
        #pragma unroll
        for (int m = 0; m < 8; ++m) {
            int row = orow0 + m * 16;
            #pragma unroll
            for (int rr = 0; rr < 4; ++rr) {
                out[(size_t)(row + rr) * N_DIM + col] = (float)acc[m][n][rr] * sprod + bv;
            }
        }
    }
}

extern "C" void kernel_launch(void* const* d_in, const int* in_sizes, int n_in,
                              void* d_out, int out_size, void* d_ws, size_t ws_size,
                              hipStream_t stream) {
    const float* x    = (const float*)d_in[0];   // [8192, 4096]
    const float* wgt  = (const float*)d_in[1];   // [4096, 4096]
    const float* bias = (const float*)d_in[2];   // [4096]
    float* out = (float*)d_out;

    char* ws = (char*)d_ws;
    float* finals   = (float*)ws;
    float* partials = (float*)(ws + 256);
    signed char* qx = (signed char*)(ws + 16384);
    signed char* qw = qx + (size_t)M_DIM * K_DIM;

    w8a8_absmax_kernel<<<NB_TOT, 256, 0, stream>>>(x, wgt, partials);
    w8a8_finalize_kernel<<<2, 256, 0, stream>>>(partials, finals);
    w8a8_quant_kernel<<<NB_TOT, 256, 0, stream>>>(x, wgt, (unsigned*)qx, (unsigned*)qw, finals);
    w8a8_gemm_kernel<<<(M_DIM / BM) * (N_DIM / BN), 512, 0, stream>>>(qx, qw, bias, finals, out);
}